// Round 6
// baseline (106.708 us; speedup 1.0000x reference)
//
#include <hip/hip_runtime.h>

#define NT 24
#define SQ 1024
#define NB 1024
#define NSEG 128
#define LSEG 8
#define WUP 8
#define CH 4

typedef float f32x16 __attribute__((ext_vector_type(16)));
typedef short bf16x8 __attribute__((ext_vector_type(8)));
typedef unsigned int uint2v __attribute__((ext_vector_type(2)));

__device__ __forceinline__ unsigned short bfrnd(float x) {
    unsigned u = __float_as_uint(x);
    return (unsigned short)((u + 0x7fffu + ((u >> 16) & 1u)) >> 16);
}
__device__ __forceinline__ unsigned cvtpk(float lo, float hi) {
    unsigned r;
    asm("v_cvt_pk_bf16_f32 %0, %1, %2" : "=v"(r) : "v"(lo), "v"(hi));
    return r;
}

// Per-chunk prefetch bundle (all static-indexed -> registers).
struct Pref {
    float em[CH][12];   // em[k][r]: row R(r)=(r&3)+8*(r>>2)+4*hi of batch c
    int4 msk;           // mask[c][t0..t0+3]
    int tg[2], tgp[2];  // numerator tags, items i=0,1 at t=t0+2*hi+i
    float gem[2];       // feature[b][t][tag_t]
};

template<bool TAGS>
__device__ __forceinline__ void pf_load(
    Pref& pf, const float* __restrict__ fbl, const int* __restrict__ tbl,
    const int* __restrict__ mbl, int t0, int hi)
{
#pragma unroll
    for (int k = 0; k < CH; ++k) {
        const float* r = fbl + (size_t)(t0 + k) * NT + hi * 4;
        float4 e0 = *(const float4*)(r);
        float4 e1 = *(const float4*)(r + 8);
        float4 e2 = *(const float4*)(r + 16);
        pf.em[k][0] = e0.x; pf.em[k][1] = e0.y; pf.em[k][2] = e0.z; pf.em[k][3] = e0.w;
        pf.em[k][4] = e1.x; pf.em[k][5] = e1.y; pf.em[k][6] = e1.z; pf.em[k][7] = e1.w;
        pf.em[k][8] = e2.x; pf.em[k][9] = e2.y; pf.em[k][10] = e2.z; pf.em[k][11] = e2.w;
    }
    pf.msk = *(const int4*)(mbl + t0);
    if (TAGS) {
#pragma unroll
        for (int i = 0; i < 2; ++i) {
            int t = t0 + 2 * hi + i;
            pf.tg[i] = tbl[t];
            pf.tgp[i] = tbl[t > 0 ? t - 1 : 0];
            pf.gem[i] = fbl[(size_t)t * NT + pf.tg[i]];
        }
    }
}

// MODE: 0 normal, 1 first chunk of sequence (t=0 init), 3 warmup (no numerator)
template<int MODE>
__device__ __forceinline__ void run_chunk(
    const Pref& pf, bf16x8 A1, bf16x8 A2,
    const float* __restrict__ ldsT, const float* __restrict__ ldsS,
    int hi, float (&w)[12], float& lz2, float& numAcc, int& cnt)
{
    // ---- numerator: 4 steps x 32 batches, 2 items per lane (off w-chain) ----
    if (MODE != 3) {
#pragma unroll
        for (int i = 0; i < 2; ++i) {
            int mlo = (i == 0) ? pf.msk.x : pf.msk.y;
            int mhi = (i == 0) ? pf.msk.z : pf.msk.w;
            int m = hi ? mhi : mlo;
            float contrib;
            if (MODE == 1 && hi == 0 && i == 0)
                contrib = ldsS[pf.tg[0]] + pf.gem[0];   // t=0: start+em0, unmasked
            else
                contrib = m ? (ldsT[pf.tgp[i] * NT + pf.tg[i]] + pf.gem[i]) : 0.0f;
            numAcc += contrib;
        }
        if (hi == 0)
            cnt += (pf.msk.x ? 1 : 0) + (pf.msk.y ? 1 : 0) +
                   (pf.msk.z ? 1 : 0) + (pf.msk.w ? 1 : 0);
    }
    // ---- w recurrence: 4 steps, all in registers ----
#pragma unroll
    for (int k = 0; k < CH; ++k) {
        int mkk = (k == 0) ? pf.msk.x : (k == 1) ? pf.msk.y : (k == 2) ? pf.msk.z : pf.msk.w;
        if (MODE == 1 && k == 0) {
#pragma unroll
            for (int r = 0; r < 12; ++r) {
                int R = (r & 3) + 8 * (r >> 2);
                w[r] = __expf(ldsS[R + 4 * hi] + pf.em[0][r]);
            }
            continue;
        }
        // B = bf16(W) in MFMA-B layout via cvt_pk + permlane32_swap.
        // Semantics f(x,y)->(x',y'): x' = {x_lo, y_lo(partner)}, y' = {x_hi(partner), y_hi}.
        unsigned aw = cvtpk(w[0], w[1]);
        unsigned bw = cvtpk(w[2], w[3]);
        unsigned cw = cvtpk(w[4], w[5]);
        unsigned dw = cvtpk(w[6], w[7]);
        unsigned ew = cvtpk(w[8], w[9]);
        unsigned fw = cvtpk(w[10], w[11]);
        uint2v s1 = __builtin_amdgcn_permlane32_swap(aw, cw, false, false);
        uint2v s2 = __builtin_amdgcn_permlane32_swap(bw, dw, false, false);
        uint2v s3 = __builtin_amdgcn_permlane32_swap(ew, 0u, false, false);
        uint2v s4 = __builtin_amdgcn_permlane32_swap(fw, 0u, false, false);
        union { unsigned u[4]; bf16x8 v; } B1, B2;
        B1.u[0] = s1[0]; B1.u[1] = s2[0]; B1.u[2] = s1[1]; B1.u[3] = s2[1];
        B2.u[0] = s3[0]; B2.u[1] = s4[0]; B2.u[2] = s3[1]; B2.u[3] = s4[1];
        f32x16 acc = {};
        acc = __builtin_amdgcn_mfma_f32_32x32x16_bf16(A1, B1.v, acc, 0, 0, 0);
        acc = __builtin_amdgcn_mfma_f32_32x32x16_bf16(A2, B2.v, acc, 0, 0, 0);
        bool m = (mkk != 0);
#pragma unroll
        for (int r = 0; r < 12; ++r) {
            float q = acc[r] * __expf(pf.em[k][r]);
            w[r] = m ? q : w[r];
        }
        if (k == CH - 1) {  // renormalize once per chunk (invariant exact)
            float zh = ((w[0] + w[1]) + (w[2] + w[3])) +
                       ((w[4] + w[5]) + (w[6] + w[7])) +
                       ((w[8] + w[9]) + (w[10] + w[11]));
            float zt = zh + __shfl_xor(zh, 32);
            float rz = __builtin_amdgcn_rcpf(zt);
            lz2 += __log2f(zt);
#pragma unroll
            for (int r = 0; r < 12; ++r) w[r] *= rz;
        }
    }
}

extern "C" __global__ void __launch_bounds__(64, 4)
crf_fwd(const float* __restrict__ feat,   // [B, S, NT]
        const int* __restrict__ maskp,    // [B, S]
        const int* __restrict__ target,   // [B, S]
        const float* __restrict__ startT, const float* __restrict__ endT,
        const float* __restrict__ trans,  // [NT, NT]
        float* __restrict__ dP, float* __restrict__ nP, int* __restrict__ cP)
{
    __shared__ float ldsT[NT * NT];
    __shared__ float ldsS[NT];
    __shared__ float ldsE[NT];

    const int tid = threadIdx.x;
    const int hi = tid >> 5;
    const int c = tid & 31;
    const int grp = blockIdx.x;          // 4096 groups = (bg, p)
    const int bg = grp >> 7;             // NSEG = 128
    const int p = grp & (NSEG - 1);
    const int b = bg * 32 + c;

    for (int i = tid; i < NT * NT; i += 64) ldsT[i] = trans[i];
    if (tid < NT) { ldsS[tid] = startT[tid]; ldsE[tid] = endT[tid]; }
    __syncthreads();

    // A = exp(trans^T) constant frags: A[row=c][k] = exp(trans[k][c]), pad 0
    union { unsigned short s[8]; bf16x8 v; } A1u, A2u;
#pragma unroll
    for (int j = 0; j < 8; ++j) {
        int k1 = 8 * hi + j;
        float v1 = (c < NT && k1 < NT) ? __expf(ldsT[k1 * NT + c]) : 0.0f;
        A1u.s[j] = bfrnd(v1);
        int k2 = 16 + 8 * hi + j;
        float v2 = (c < NT && k2 < NT) ? __expf(ldsT[k2 * NT + c]) : 0.0f;
        A2u.s[j] = bfrnd(v2);
    }

    const float* fbl = feat + (size_t)b * SQ * NT;
    const int* tbl = target + (size_t)b * SQ;
    const int* mbl = maskp + (size_t)b * SQ;

    float w[12];
    float lz2 = 0.0f, sub2 = 0.0f, numAcc = 0.0f;
    int cnt = 0;
    const int a = p * LSEG;
    Pref pfA, pfB;

    if (p > 0) {
#pragma unroll
        for (int r = 0; r < 12; ++r) w[r] = 1.0f;   // uniform seed
        // 8-step warmup (2 chunks): contraction ~0.1/step -> direction error
        // ~1e-8 by segment start; telescoping sub2 cancels the arbitrary scale.
        pf_load<false>(pfA, fbl, tbl, mbl, a - 8, hi);
        pf_load<false>(pfB, fbl, tbl, mbl, a - 4, hi);
        run_chunk<3>(pfA, A1u.v, A2u.v, ldsT, ldsS, hi, w, lz2, numAcc, cnt);
        pf_load<true>(pfA, fbl, tbl, mbl, a, hi);
        run_chunk<3>(pfB, A1u.v, A2u.v, ldsT, ldsS, hi, w, lz2, numAcc, cnt);
        pf_load<true>(pfB, fbl, tbl, mbl, a + 4, hi);
        // capture segment-start scale (state = w_{a-1})
        float zh = ((w[0] + w[1]) + (w[2] + w[3])) + ((w[4] + w[5]) + (w[6] + w[7])) +
                   ((w[8] + w[9]) + (w[10] + w[11]));
        float zt = zh + __shfl_xor(zh, 32);
        sub2 = lz2 + __log2f(zt);
        run_chunk<0>(pfA, A1u.v, A2u.v, ldsT, ldsS, hi, w, lz2, numAcc, cnt);
        run_chunk<0>(pfB, A1u.v, A2u.v, ldsT, ldsS, hi, w, lz2, numAcc, cnt);
    } else {
        pf_load<true>(pfA, fbl, tbl, mbl, 0, hi);
        pf_load<true>(pfB, fbl, tbl, mbl, 4, hi);
        run_chunk<1>(pfA, A1u.v, A2u.v, ldsT, ldsS, hi, w, lz2, numAcc, cnt);
        run_chunk<0>(pfB, A1u.v, A2u.v, ldsT, ldsS, hi, w, lz2, numAcc, cnt);
    }

    // ---- segment epilogue ----
    float ze = 0.0f;
#pragma unroll
    for (int r = 0; r < 12; ++r) {
        int R = (r & 3) + 8 * (r >> 2) + 4 * hi;
        float wv = w[r];
        if (p == NSEG - 1) wv *= __expf(ldsE[R]);
        ze += wv;
    }
    float zt = ze + __shfl_xor(ze, 32);
    float res = (lz2 + __log2f(zt) - sub2) * 0.6931471805599453f;
    float ntot = numAcc + __shfl_xor(numAcc, 32);
    if (hi == 0) {
        dP[p * NB + b] = res;
        nP[p * NB + b] = ntot;
        cP[p * NB + b] = cnt;
    }
}

extern "C" __global__ void __launch_bounds__(64)
crf_combine(const float* __restrict__ dP, const float* __restrict__ nP,
            const int* __restrict__ cP, const int* __restrict__ target,
            const float* __restrict__ endT, float* __restrict__ bpart)
{
    const int b = blockIdx.x * 64 + threadIdx.x;
    float den = 0.f, num = 0.f;
    int cnt = 0;
#pragma unroll 8
    for (int p = 0; p < NSEG; ++p) {
        den += dP[p * NB + b];
        num += nP[p * NB + b];
        cnt += cP[p * NB + b];
    }
    int lastTag = target[(size_t)b * SQ + (cnt - 1)];
    float llh = (num + endT[lastTag]) - den;
#pragma unroll
    for (int m = 1; m < 64; m <<= 1) llh += __shfl_xor(llh, m, 64);
    if (threadIdx.x == 0) bpart[blockIdx.x] = llh;
}

extern "C" __global__ void __launch_bounds__(64)
crf_final(const float* __restrict__ bpart, float* __restrict__ out)
{
    float s = (threadIdx.x < NB / 64) ? bpart[threadIdx.x] : 0.0f;
#pragma unroll
    for (int m = 1; m < 64; m <<= 1) s += __shfl_xor(s, m, 64);
    if (threadIdx.x == 0) out[0] = -s * (1.0f / NB);
}

extern "C" void kernel_launch(void* const* d_in, const int* in_sizes, int n_in,
                              void* d_out, int out_size, void* d_ws, size_t ws_size,
                              hipStream_t stream)
{
    const float* feat   = (const float*)d_in[0];
    const int*   maskp  = (const int*)d_in[1];
    const int*   target = (const int*)d_in[2];
    const float* startT = (const float*)d_in[3];
    const float* endT   = (const float*)d_in[4];
    const float* trans  = (const float*)d_in[5];

    float* dP = (float*)d_ws;                    // [NSEG*NB]
    float* nP = dP + NSEG * NB;                  // [NSEG*NB]
    int*   cP = (int*)(nP + NSEG * NB);          // [NSEG*NB]
    float* bpart = (float*)(cP + NSEG * NB);     // [NB/64]

    crf_fwd<<<(NB / 32) * NSEG, 64, 0, stream>>>(feat, maskp, target, startT, endT,
                                                 trans, dP, nP, cP);
    crf_combine<<<NB / 64, 64, 0, stream>>>(dP, nP, cP, target, endT, bpart);
    crf_final<<<1, 64, 0, stream>>>(bpart, (float*)d_out);
}

// Round 7
// 47.397 us; speedup vs baseline: 2.2513x; 2.2513x over previous
//
#include <hip/hip_runtime.h>

#define NT 24
#define SQ 1024
#define NB 1024
#define NSEG 32
#define LSEG 32
#define TS 8                 // steps per LDS tile
#define LPAD 194             // dwords per batch row in LDS (192 + 2; keeps 8B align, 2-way banks)

typedef float f32x16 __attribute__((ext_vector_type(16)));
typedef short bf16x8 __attribute__((ext_vector_type(8)));
typedef unsigned int uint2v __attribute__((ext_vector_type(2)));

__device__ __forceinline__ unsigned short bfrnd(float x) {
    unsigned u = __float_as_uint(x);
    return (unsigned short)((u + 0x7fffu + ((u >> 16) & 1u)) >> 16);
}
__device__ __forceinline__ unsigned cvtpk(float lo, float hi) {
    unsigned r;
    asm("v_cvt_pk_bf16_f32 %0, %1, %2" : "=v"(r) : "v"(lo), "v"(hi));
    return r;
}

// Issue one 8-step tile's global loads into registers (coalesced 128B runs)
// + the tile's packed tag/mask u64 (2 cache lines for the whole wave).
__device__ __forceinline__ void stage_issue(
    float4 (&pre)[24], unsigned long long& tg,
    const float* __restrict__ fbase, const unsigned long long* __restrict__ tagT,
    int t0, int sg, int sf, int b)
{
#pragma unroll
    for (int q = 0; q < 24; ++q) {
        int sb = 8 * (q & 3) + sg;       // batch within group (0..31)
        int f4 = 8 * (q >> 2) + sf;      // float4 within 8x24 tile span (0..47)
        pre[q] = *(const float4*)(fbase + ((size_t)sb * SQ + (size_t)t0) * NT + f4 * 4);
    }
    tg = tagT[(size_t)(t0 >> 3) * NB + b];
}

__device__ __forceinline__ void stage_write(
    const float4 (&pre)[24], float* __restrict__ ldsEm, int sg, int sf)
{
#pragma unroll
    for (int q = 0; q < 24; ++q) {
        int sb = 8 * (q & 3) + sg;
        int f4 = 8 * (q >> 2) + sf;
        float2* d = (float2*)&ldsEm[sb * LPAD + f4 * 4];
        d[0] = make_float2(pre[q].x, pre[q].y);
        d[1] = make_float2(pre[q].z, pre[q].w);
    }
}

// MODE: 0 normal, 1 first tile of the whole sequence (t=0 init), 3 warmup.
template<int MODE>
__device__ __forceinline__ void tile_compute(
    unsigned long long tg64, unsigned pbyte,
    bf16x8 A1, bf16x8 A2,
    const float* __restrict__ ldsEm, const float* __restrict__ ldsT,
    const float* __restrict__ ldsS,
    int hi, int c, float (&w)[12], float& lz2, float& numAcc, int& cnt)
{
    // ---- numerator: lane (hi,c) owns steps k = hi*4 + i of batch c ----
    if (MODE != 3) {
#pragma unroll
        for (int i = 0; i < 4; ++i) {
            int k = hi * 4 + i;
            int by = (int)(tg64 >> (8 * k)) & 255;
            int tg = by & 31;
            int m = by >> 7;
            int pv = (k == 0) ? (int)(pbyte & 31) : ((int)(tg64 >> (8 * k - 8)) & 31);
            float emv = ldsEm[c * LPAD + k * NT + tg];
            float contrib;
            if (MODE == 1 && hi == 0 && i == 0)
                contrib = ldsS[tg] + emv;            // t=0: start+em0, unmasked
            else
                contrib = m ? (ldsT[pv * NT + tg] + emv) : 0.0f;
            numAcc += contrib;
            cnt += m;
        }
    }
    // ---- w recurrence: 8 steps from LDS, state in registers ----
#pragma unroll
    for (int k = 0; k < TS; ++k) {
        const float2* ep = (const float2*)&ldsEm[c * LPAD + k * NT + 4 * hi];
        float2 e0 = ep[0], e1 = ep[1], e2 = ep[4], e3 = ep[5], e4 = ep[8], e5 = ep[9];
        float ee[12] = {e0.x, e0.y, e1.x, e1.y, e2.x, e2.y,
                        e3.x, e3.y, e4.x, e4.y, e5.x, e5.y};
        if (MODE == 1 && k == 0) {
#pragma unroll
            for (int r = 0; r < 12; ++r) {
                int R = (r & 3) + 8 * (r >> 2) + 4 * hi;
                w[r] = __expf(ldsS[R] + ee[r]);
            }
            continue;
        }
        int m = (int)(tg64 >> (8 * k + 7)) & 1;
        // B = bf16(W) in MFMA-B layout via cvt_pk + permlane32_swap
        unsigned aw = cvtpk(w[0], w[1]);
        unsigned bw = cvtpk(w[2], w[3]);
        unsigned cw = cvtpk(w[4], w[5]);
        unsigned dw = cvtpk(w[6], w[7]);
        unsigned ew = cvtpk(w[8], w[9]);
        unsigned fw = cvtpk(w[10], w[11]);
        uint2v s1 = __builtin_amdgcn_permlane32_swap(aw, cw, false, false);
        uint2v s2 = __builtin_amdgcn_permlane32_swap(bw, dw, false, false);
        uint2v s3 = __builtin_amdgcn_permlane32_swap(ew, 0u, false, false);
        uint2v s4 = __builtin_amdgcn_permlane32_swap(fw, 0u, false, false);
        union { unsigned u[4]; bf16x8 v; } B1, B2;
        B1.u[0] = s1[0]; B1.u[1] = s2[0]; B1.u[2] = s1[1]; B1.u[3] = s2[1];
        B2.u[0] = s3[0]; B2.u[1] = s4[0]; B2.u[2] = s3[1]; B2.u[3] = s4[1];
        f32x16 acc = {};
        acc = __builtin_amdgcn_mfma_f32_32x32x16_bf16(A1, B1.v, acc, 0, 0, 0);
        acc = __builtin_amdgcn_mfma_f32_32x32x16_bf16(A2, B2.v, acc, 0, 0, 0);
#pragma unroll
        for (int r = 0; r < 12; ++r) {
            float q = acc[r] * __expf(ee[r]);
            w[r] = m ? q : w[r];
        }
        if ((k & 3) == 3) {   // renormalize every 4 steps (invariant exact)
            float zh = ((w[0] + w[1]) + (w[2] + w[3])) +
                       ((w[4] + w[5]) + (w[6] + w[7])) +
                       ((w[8] + w[9]) + (w[10] + w[11]));
            float zt = zh + __shfl_xor(zh, 32);
            float rz = __builtin_amdgcn_rcpf(zt);
            lz2 += __log2f(zt);
#pragma unroll
            for (int r = 0; r < 12; ++r) w[r] *= rz;
        }
    }
}

// Pack tag|mask<<7 bytes into transposed u64 octets: tagT[t/8][b].
extern "C" __global__ void __launch_bounds__(128)
crf_pack(const int* __restrict__ target, const int* __restrict__ maskp,
         unsigned long long* __restrict__ tagT)
{
    const int b = blockIdx.x;
    const int oct = threadIdx.x;      // 0..127
    const int* tb = target + (size_t)b * SQ + oct * 8;
    const int* mb = maskp + (size_t)b * SQ + oct * 8;
    int4 t0 = *(const int4*)tb, t1 = *(const int4*)(tb + 4);
    int4 m0 = *(const int4*)mb, m1 = *(const int4*)(mb + 4);
    int tg[8] = {t0.x, t0.y, t0.z, t0.w, t1.x, t1.y, t1.z, t1.w};
    int mk[8] = {m0.x, m0.y, m0.z, m0.w, m1.x, m1.y, m1.z, m1.w};
    unsigned long long v = 0;
#pragma unroll
    for (int i = 0; i < 8; ++i)
        v |= (unsigned long long)((tg[i] & 31) | (mk[i] ? 128 : 0)) << (8 * i);
    tagT[(size_t)oct * NB + b] = v;
}

extern "C" __global__ void __launch_bounds__(64, 1)
crf_fwd(const float* __restrict__ feat,
        const float* __restrict__ startT, const float* __restrict__ endT,
        const float* __restrict__ trans,
        const unsigned long long* __restrict__ tagT,
        float* __restrict__ dP, float* __restrict__ nP, int* __restrict__ cP)
{
    __shared__ float ldsT[NT * NT];
    __shared__ float ldsS[NT];
    __shared__ float ldsE[NT];
    __shared__ __align__(16) float ldsEm[32 * LPAD];

    const int tid = threadIdx.x;
    const int hi = tid >> 5;
    const int c = tid & 31;
    const int sg = tid >> 3;          // staging: batch-octet lane group (0..7)
    const int sf = tid & 7;           // staging: f4 within run
    const int grp = blockIdx.x;       // 1024 groups = (bg, p)
    const int bg = grp >> 5;          // NSEG = 32
    const int p = grp & (NSEG - 1);
    const int b = bg * 32 + c;

    for (int i = tid; i < NT * NT; i += 64) ldsT[i] = trans[i];
    if (tid < NT) { ldsS[tid] = startT[tid]; ldsE[tid] = endT[tid]; }
    __syncthreads();

    // A = exp(trans^T) constant frags: A[row=c][k] = exp(trans[k][c]), pad 0
    union { unsigned short s[8]; bf16x8 v; } A1u, A2u;
#pragma unroll
    for (int j = 0; j < 8; ++j) {
        int k1 = 8 * hi + j;
        float v1 = (c < NT && k1 < NT) ? __expf(ldsT[k1 * NT + c]) : 0.0f;
        A1u.s[j] = bfrnd(v1);
        int k2 = 16 + 8 * hi + j;
        float v2 = (c < NT && k2 < NT) ? __expf(ldsT[k2 * NT + c]) : 0.0f;
        A2u.s[j] = bfrnd(v2);
    }

    const float* fbase = feat + (size_t)bg * 32 * SQ * NT;

    float w[12];
#pragma unroll
    for (int r = 0; r < 12; ++r) w[r] = 1.0f;
    float lz2 = 0.0f, sub2 = 0.0f, numAcc = 0.0f;
    int cnt = 0;
    unsigned pbyte = 0;
    const int a = p * LSEG;

    float4 pre[24];
    unsigned long long tgC, tgN;

    if (p > 0) {
        // ---- 8-step warmup tile ----
        unsigned long long tgW;
        stage_issue(pre, tgW, fbase, tagT, a - TS, sg, sf, b);
        stage_write(pre, ldsEm, sg, sf);
        __syncthreads();
        stage_issue(pre, tgC, fbase, tagT, a, sg, sf, b);
        tile_compute<3>(tgW, pbyte, A1u.v, A2u.v, ldsEm, ldsT, ldsS,
                        hi, c, w, lz2, numAcc, cnt);
        pbyte = (unsigned)(tgW >> 56);
        // capture segment-start scale (state = w_{a-1}): cancels warmup init
        float zh = ((w[0] + w[1]) + (w[2] + w[3])) + ((w[4] + w[5]) + (w[6] + w[7])) +
                   ((w[8] + w[9]) + (w[10] + w[11]));
        float zt = zh + __shfl_xor(zh, 32);
        sub2 = lz2 + __log2f(zt);
#pragma unroll 1
        for (int mt = 0; mt < 4; ++mt) {
            stage_write(pre, ldsEm, sg, sf);
            __syncthreads();
            tgN = 0;
            if (mt < 3) stage_issue(pre, tgN, fbase, tagT, a + TS * (mt + 1), sg, sf, b);
            tile_compute<0>(tgC, pbyte, A1u.v, A2u.v, ldsEm, ldsT, ldsS,
                            hi, c, w, lz2, numAcc, cnt);
            pbyte = (unsigned)(tgC >> 56);
            tgC = tgN;
        }
    } else {
        stage_issue(pre, tgC, fbase, tagT, 0, sg, sf, b);
        stage_write(pre, ldsEm, sg, sf);
        __syncthreads();
        stage_issue(pre, tgN, fbase, tagT, TS, sg, sf, b);
        tile_compute<1>(tgC, pbyte, A1u.v, A2u.v, ldsEm, ldsT, ldsS,
                        hi, c, w, lz2, numAcc, cnt);
        pbyte = (unsigned)(tgC >> 56);
        tgC = tgN;
#pragma unroll 1
        for (int mt = 1; mt < 4; ++mt) {
            stage_write(pre, ldsEm, sg, sf);
            __syncthreads();
            tgN = 0;
            if (mt < 3) stage_issue(pre, tgN, fbase, tagT, TS * (mt + 1), sg, sf, b);
            tile_compute<0>(tgC, pbyte, A1u.v, A2u.v, ldsEm, ldsT, ldsS,
                            hi, c, w, lz2, numAcc, cnt);
            pbyte = (unsigned)(tgC >> 56);
            tgC = tgN;
        }
    }

    // ---- segment epilogue ----
    float ze = 0.0f;
#pragma unroll
    for (int r = 0; r < 12; ++r) {
        int R = (r & 3) + 8 * (r >> 2) + 4 * hi;
        float wv = w[r];
        if (p == NSEG - 1) wv *= __expf(ldsE[R]);
        ze += wv;
    }
    float zt = ze + __shfl_xor(ze, 32);
    float res = (lz2 + __log2f(zt) - sub2) * 0.6931471805599453f;
    float ntot = numAcc + __shfl_xor(numAcc, 32);
    int ctot = cnt + __shfl_xor(cnt, 32);
    if (hi == 0) {
        dP[p * NB + b] = res;
        nP[p * NB + b] = ntot;
        cP[p * NB + b] = ctot;
    }
}

extern "C" __global__ void __launch_bounds__(64)
crf_combine(const float* __restrict__ dP, const float* __restrict__ nP,
            const int* __restrict__ cP, const int* __restrict__ target,
            const float* __restrict__ endT, float* __restrict__ bpart)
{
    const int b = blockIdx.x * 64 + threadIdx.x;
    float den = 0.f, num = 0.f;
    int cnt = 0;
#pragma unroll 8
    for (int p = 0; p < NSEG; ++p) {
        den += dP[p * NB + b];
        num += nP[p * NB + b];
        cnt += cP[p * NB + b];
    }
    int lastTag = target[(size_t)b * SQ + (cnt - 1)];
    float llh = (num + endT[lastTag]) - den;
#pragma unroll
    for (int m = 1; m < 64; m <<= 1) llh += __shfl_xor(llh, m, 64);
    if (threadIdx.x == 0) bpart[blockIdx.x] = llh;
}

extern "C" __global__ void __launch_bounds__(64)
crf_final(const float* __restrict__ bpart, float* __restrict__ out)
{
    float s = (threadIdx.x < NB / 64) ? bpart[threadIdx.x] : 0.0f;
#pragma unroll
    for (int m = 1; m < 64; m <<= 1) s += __shfl_xor(s, m, 64);
    if (threadIdx.x == 0) out[0] = -s * (1.0f / NB);
}

extern "C" void kernel_launch(void* const* d_in, const int* in_sizes, int n_in,
                              void* d_out, int out_size, void* d_ws, size_t ws_size,
                              hipStream_t stream)
{
    const float* feat   = (const float*)d_in[0];
    const int*   maskp  = (const int*)d_in[1];
    const int*   target = (const int*)d_in[2];
    const float* startT = (const float*)d_in[3];
    const float* endT   = (const float*)d_in[4];
    const float* trans  = (const float*)d_in[5];

    unsigned long long* tagT = (unsigned long long*)d_ws;   // [SQ/8 * NB] = 1 MB
    float* dP = (float*)(tagT + (SQ / 8) * NB);             // [NSEG*NB]
    float* nP = dP + NSEG * NB;                             // [NSEG*NB]
    int*   cP = (int*)(nP + NSEG * NB);                     // [NSEG*NB]
    float* bpart = (float*)(cP + NSEG * NB);                // [NB/64]

    crf_pack<<<NB, 128, 0, stream>>>(target, maskp, tagT);
    crf_fwd<<<(NB / 32) * NSEG, 64, 0, stream>>>(feat, startT, endT, trans, tagT,
                                                 dP, nP, cP);
    crf_combine<<<NB / 64, 64, 0, stream>>>(dP, nP, cP, target, endT, bpart);
    crf_final<<<1, 64, 0, stream>>>(bpart, (float*)d_out);
}